// Round 13
// baseline (313.066 us; speedup 1.0000x reference)
//
#include <hip/hip_runtime.h>
#include <math.h>
#include <stdint.h>

// ---- problem constants ----
// x: [8,1,512,512] fp32; 8x8 patches -> 4096 patches/batch, pdim=64, HID=8.
// Output [8,512,512,3] fp32.
static constexpr float QSCALE = 0.35355339059327373f * 1.4426950408889634f; // SCALE*log2(e)

typedef _Float16 half8f __attribute__((ext_vector_type(8)));
typedef _Float16 half4f __attribute__((ext_vector_type(4)));
typedef float f32x4 __attribute__((ext_vector_type(4)));

__device__ __forceinline__ ushort f16_bits(float x) {
    return __builtin_bit_cast(ushort, (_Float16)x);
}
__device__ __forceinline__ float f16_back(ushort u) {
    return (float)__builtin_bit_cast(_Float16, u);
}
__device__ __forceinline__ uint pkrtz_bits(float a, float b) {
    auto v = __builtin_amdgcn_cvt_pkrtz(a, b);   // __fp16 ext_vector(2)
    return __builtin_bit_cast(uint, v);
}

// =====================================================================
// Packed-operand writer shared by both prepack kernels.
// Qpack[p]: 32 f16 slots = [q_hi(8), q_lo(8), q_hi(8), 0(8)]   (64 B)
// Kpack[p]: [k_hi(8), k_hi(8), k_lo(8), 0(8)]                  (64 B)
//   -> one 16x16x32 MFMA gives s = qh·kh + ql·kh + qh·kl  (fp32-class)
// VpackT[b][d][key] f16, d<8 = v_d, d=8 = 1.0 (rowsum column)
// =====================================================================
__device__ __forceinline__ void write_packed(
    int p, const float* qv, const float* kv, const float* vv,
    uint* __restrict__ Qpack, uint* __restrict__ Kpack, ushort* __restrict__ VpackT)
{
    uint qw[8], kw[8];
    #pragma unroll
    for (int i = 0; i < 4; ++i) {
        float q0 = qv[2*i], q1 = qv[2*i+1];
        ushort qh0 = f16_bits(q0), qh1 = f16_bits(q1);
        ushort ql0 = f16_bits(q0 - f16_back(qh0));
        ushort ql1 = f16_bits(q1 - f16_back(qh1));
        qw[i]   = (uint)qh0 | ((uint)qh1 << 16);
        qw[4+i] = (uint)ql0 | ((uint)ql1 << 16);
        float k0 = kv[2*i], k1 = kv[2*i+1];
        ushort kh0 = f16_bits(k0), kh1 = f16_bits(k1);
        ushort kl0 = f16_bits(k0 - f16_back(kh0));
        ushort kl1 = f16_bits(k1 - f16_back(kh1));
        kw[i]   = (uint)kh0 | ((uint)kh1 << 16);
        kw[4+i] = (uint)kl0 | ((uint)kl1 << 16);
    }
    uint4* Qp = (uint4*)(Qpack + (size_t)p*16);
    Qp[0] = make_uint4(qw[0],qw[1],qw[2],qw[3]);
    Qp[1] = make_uint4(qw[4],qw[5],qw[6],qw[7]);
    Qp[2] = make_uint4(qw[0],qw[1],qw[2],qw[3]);
    Qp[3] = make_uint4(0,0,0,0);
    uint4* Kp = (uint4*)(Kpack + (size_t)p*16);
    Kp[0] = make_uint4(kw[0],kw[1],kw[2],kw[3]);
    Kp[1] = make_uint4(kw[0],kw[1],kw[2],kw[3]);
    Kp[2] = make_uint4(kw[4],kw[5],kw[6],kw[7]);
    Kp[3] = make_uint4(0,0,0,0);
    int b = p >> 12, pidx = p & 4095;
    #pragma unroll
    for (int d = 0; d < 8; ++d)
        VpackT[((size_t)(b*16 + d))*4096 + pidx] = f16_bits(vv[d]);
    VpackT[((size_t)(b*16 + 8))*4096 + pidx] = 0x3C00; // 1.0
}

// =====================================================================
// Kernel 1: patchify + QKV projection (64 -> 8 x3) + f16 packing
// =====================================================================
__global__ __launch_bounds__(256) void qkv_prepack_kernel(
    const float* __restrict__ x,
    const float* __restrict__ Wq, const float* __restrict__ bq,
    const float* __restrict__ Wk, const float* __restrict__ bk,
    const float* __restrict__ Wv, const float* __restrict__ bv,
    uint* __restrict__ Qpack, uint* __restrict__ Kpack, ushort* __restrict__ VpackT)
{
    __shared__ float sW[64*24 + 24];
    for (int i = threadIdx.x; i < 64*24 + 24; i += 256) {
        float w;
        if (i < 1536) {
            int j = i / 24, c = i % 24;
            w = (c < 8) ? Wq[j*8 + c] : (c < 16) ? Wk[j*8 + (c-8)] : Wv[j*8 + (c-16)];
        } else {
            int c = i - 1536;
            w = (c < 8) ? bq[c] : (c < 16) ? bk[c-8] : bv[c-16];
        }
        sW[i] = w;
    }
    __syncthreads();

    int p = blockIdx.x * 256 + threadIdx.x;
    int b    = p >> 12;
    int pidx = p & 4095;
    int pr = pidx >> 6, pc = pidx & 63;
    const float* xb = x + ((size_t)(b*512 + pr*8)) * 512 + (size_t)pc*8;

    float acc[24];
    #pragma unroll
    for (int o = 0; o < 24; ++o) acc[o] = sW[1536 + o];
    #pragma unroll
    for (int i = 0; i < 8; ++i) {
        float4 a = *(const float4*)(xb + (size_t)i*512);
        float4 c = *(const float4*)(xb + (size_t)i*512 + 4);
        float px[8] = {a.x, a.y, a.z, a.w, c.x, c.y, c.z, c.w};
        #pragma unroll
        for (int jj = 0; jj < 8; ++jj) {
            float pj = px[jj];
            const float* w = &sW[(i*8 + jj)*24];
            #pragma unroll
            for (int o = 0; o < 24; ++o) acc[o] += pj * w[o];
        }
    }
    float qv[8], kv[8], vv[8];
    #pragma unroll
    for (int o = 0; o < 8; ++o) {
        qv[o] = acc[o] * QSCALE;
        kv[o] = acc[8+o];
        vv[o] = acc[16+o];
    }
    write_packed(p, qv, kv, vv, Qpack, Kpack, VpackT);
}

// =====================================================================
// MFMA flash-attention partial pass, v2 (LDS-free, slim VALU).
// Per wave: one 16-query tile x 1024-key chunk, fully independent (no
// barriers). K read per-lane from Kpack (1KB contiguous per wave-read,
// L2-resident); V gathered from the 32KB L1-resident VpackT table.
// Per 16-key tile: 2 global loads + QK MFMA(16x16x32, hi/lo exact) +
// 4 raw v_exp_f32 + 2 cvt_pkrtz + PV MFMA(16x16x16, f16 P).
// Swapped QK (A=K,B=Q) makes the S output layout == PV A-frag layout.
// Grid: 512 q-quads x 4 chunks = 2048 blocks x 256 threads.
// =====================================================================
__global__ __launch_bounds__(256) void attn_mfma_kernel(
    const uint* __restrict__ Qpack, const uint* __restrict__ Kpack,
    const ushort* __restrict__ VpackT,
    float* __restrict__ Pacc, float* __restrict__ Psum)
{
    int tid  = threadIdx.x;
    int lane = tid & 63, wid = tid >> 6;
    int blk  = blockIdx.x;
    int c     = blk & 3;
    int qquad = blk >> 2;
    int qt  = qquad*4 + wid;          // 0..2047 global q-tile
    int b   = qt >> 8;                // batch
    int qg0 = qt * 16;                // global query base
    int kb  = b*4096 + c*1024;        // global key base
    int g = lane >> 4, cl = lane & 15;

    // Q B-fragment: lane holds Q[k_hat=(g*8..g*8+7)][q=cl]
    half8f qfrag = *(const half8f*)(Qpack + ((size_t)(qg0 + cl))*16 + g*4);

    f32x4 acc = {0.f, 0.f, 0.f, 0.f};

    // per-lane streams: K row (key = kb + t*16 + cl, 16B at word g*4),
    // V row d=cl, 4 keys starting at kb + t*16 + g*4
    const uint*   kp = Kpack  + ((size_t)(kb + cl))*16 + g*4;
    const ushort* vp = VpackT + ((size_t)(b*16 + cl))*4096 + c*1024 + g*4;

    #pragma unroll 4
    for (int t = 0; t < 64; ++t) {
        half8f kfrag = *(const half8f*)kp;          // K hi/lo packed row
        f32x4 z = {0.f, 0.f, 0.f, 0.f};
        // S^T tile: lane -> (q=cl, key_local=g*4+r)
        f32x4 s = __builtin_amdgcn_mfma_f32_16x16x32_f16(kfrag, qfrag, z, 0, 0, 0);
        float e0 = __builtin_amdgcn_exp2f(s[0]);
        float e1 = __builtin_amdgcn_exp2f(s[1]);
        float e2 = __builtin_amdgcn_exp2f(s[2]);
        float e3 = __builtin_amdgcn_exp2f(s[3]);
        uint2 pu = make_uint2(pkrtz_bits(e0, e1), pkrtz_bits(e2, e3));
        half4f pfrag = __builtin_bit_cast(half4f, pu);   // A-frag: P[q][k=g*4+i]
        half4f vfrag = __builtin_bit_cast(half4f, *(const uint2*)vp); // B: V[k=g*4+i][d=cl]
        acc = __builtin_amdgcn_mfma_f32_16x16x16f16(pfrag, vfrag, acc, 0, 0, 0);
        kp += 256;   // 16 keys * 16 words
        vp += 16;    // 16 keys
    }

    // acc: lane -> O[q = qg0 + g*4 + r][d = cl]; d=8 column = rowsum
    if (cl < 8) {
        #pragma unroll
        for (int r = 0; r < 4; ++r)
            Pacc[((size_t)c*32768 + qg0 + g*4 + r)*8 + cl] = acc[r];
    } else if (cl == 8) {
        #pragma unroll
        for (int r = 0; r < 4; ++r)
            Psum[(size_t)c*32768 + qg0 + g*4 + r] = acc[r];
    }
}

// Reduce NC partials per query -> normalized output [32768 x 8]
template<int NC>
__global__ __launch_bounds__(256) void attn_reduce_kernel(
    const float* __restrict__ Pacc, const float* __restrict__ Psum,
    float* __restrict__ O)
{
    int qg = blockIdx.x * 256 + threadIdx.x;
    float s = 0.f;
    float a[8] = {0,0,0,0,0,0,0,0};
    #pragma unroll
    for (int c = 0; c < NC; ++c) {
        s += Psum[(size_t)c*32768 + qg];
        const float4* pa = (const float4*)(Pacc + ((size_t)c*32768 + qg)*8);
        float4 x0 = pa[0], x1 = pa[1];
        a[0]+=x0.x; a[1]+=x0.y; a[2]+=x0.z; a[3]+=x0.w;
        a[4]+=x1.x; a[5]+=x1.y; a[6]+=x1.z; a[7]+=x1.w;
    }
    float inv = 1.0f / s;
    float4* o = (float4*)(O + (size_t)qg * 8);
    o[0] = make_float4(a[0]*inv, a[1]*inv, a[2]*inv, a[3]*inv);
    o[1] = make_float4(a[4]*inv, a[5]*inv, a[6]*inv, a[7]*inv);
}

// =====================================================================
// Kernel 4: second-stage projection (8 -> 8 x3) + f16 packing
// =====================================================================
__global__ __launch_bounds__(256) void proj2_prepack_kernel(
    const float* __restrict__ F,
    const float* __restrict__ Wsq, const float* __restrict__ bsq,
    const float* __restrict__ Wsk, const float* __restrict__ bsk,
    const float* __restrict__ Wsv, const float* __restrict__ bsv,
    uint* __restrict__ Qpack, uint* __restrict__ Kpack, ushort* __restrict__ VpackT)
{
    __shared__ float sW[8*24 + 24];
    for (int i = threadIdx.x; i < 8*24 + 24; i += 256) {
        float w;
        if (i < 192) {
            int j = i / 24, c = i % 24;
            w = (c < 8) ? Wsq[j*8 + c] : (c < 16) ? Wsk[j*8 + (c-8)] : Wsv[j*8 + (c-16)];
        } else {
            int c = i - 192;
            w = (c < 8) ? bsq[c] : (c < 16) ? bsk[c-8] : bsv[c-16];
        }
        sW[i] = w;
    }
    __syncthreads();

    int p = blockIdx.x * 256 + threadIdx.x;
    const float* f = F + (size_t)p * 8;
    float fv[8];
    {
        float4 a = ((const float4*)f)[0], c = ((const float4*)f)[1];
        fv[0]=a.x; fv[1]=a.y; fv[2]=a.z; fv[3]=a.w;
        fv[4]=c.x; fv[5]=c.y; fv[6]=c.z; fv[7]=c.w;
    }
    float acc[24];
    #pragma unroll
    for (int o = 0; o < 24; ++o) acc[o] = sW[192 + o];
    #pragma unroll
    for (int j = 0; j < 8; ++j) {
        float fj = fv[j];
        #pragma unroll
        for (int o = 0; o < 24; ++o) acc[o] += fj * sW[j*24 + o];
    }
    float qv[8], kv[8], vv[8];
    #pragma unroll
    for (int o = 0; o < 8; ++o) {
        qv[o] = acc[o] * QSCALE;
        kv[o] = acc[8+o];
        vv[o] = acc[16+o];
    }
    write_packed(p, qv, kv, vv, Qpack, Kpack, VpackT);
}

// =====================================================================
// Kernel 6: LayerNorm(8) + proj to 3 + clamped softplus + 8x upsample
// =====================================================================
__global__ __launch_bounds__(256) void head_kernel(
    const float* __restrict__ S,
    const float* __restrict__ ln_w, const float* __restrict__ ln_b,
    const float* __restrict__ Wp, const float* __restrict__ bp,
    float* __restrict__ out)
{
    int idx = blockIdx.x * 256 + threadIdx.x;   // 0..131071
    int p  = idx >> 2;
    int rq = idx & 3;
    int b    = p >> 12;
    int pidx = p & 4095;
    int pr = pidx >> 6, pc = pidx & 63;

    const float* s = S + (size_t)p * 8;
    float f[8];
    {
        float4 a = ((const float4*)s)[0], c = ((const float4*)s)[1];
        f[0]=a.x; f[1]=a.y; f[2]=a.z; f[3]=a.w;
        f[4]=c.x; f[5]=c.y; f[6]=c.z; f[7]=c.w;
    }
    float mu = 0.f;
    #pragma unroll
    for (int d = 0; d < 8; ++d) mu += f[d];
    mu *= 0.125f;
    float var = 0.f;
    #pragma unroll
    for (int d = 0; d < 8; ++d) { float t = f[d]-mu; var += t*t; }
    var *= 0.125f;
    float r = rsqrtf(var + 1e-5f);

    float o0 = bp[0], o1 = bp[1], o2 = bp[2];
    #pragma unroll
    for (int d = 0; d < 8; ++d) {
        float n = (f[d]-mu)*r*ln_w[d] + ln_b[d];
        o0 += n*Wp[d*3+0]; o1 += n*Wp[d*3+1]; o2 += n*Wp[d*3+2];
    }
    float o[3] = {o0, o1, o2};
    #pragma unroll
    for (int cix = 0; cix < 3; ++cix) {
        float xx = o[cix];
        float sp = fmaxf(xx, 0.f) + log1pf(expf(-fabsf(xx)));
        o[cix] = fminf(sp, 6.0f) + 1e-6f;
    }

    float4 f40 = make_float4(o[0], o[1], o[2], o[0]);
    float4 f41 = make_float4(o[1], o[2], o[0], o[1]);
    float4 f42 = make_float4(o[2], o[0], o[1], o[2]);
    float* ob = out + (((size_t)(b*512 + pr*8 + rq*2)) * 512 + (size_t)pc*8) * 3;
    #pragma unroll
    for (int i = 0; i < 2; ++i) {
        float4* row = (float4*)(ob + (size_t)i * 512 * 3);
        row[0]=f40; row[1]=f41; row[2]=f42; row[3]=f40; row[4]=f41; row[5]=f42;
    }
}

// =====================================================================
extern "C" void kernel_launch(void* const* d_in, const int* in_sizes, int n_in,
                              void* d_out, int out_size, void* d_ws, size_t ws_size,
                              hipStream_t stream)
{
    const float* x   = (const float*)d_in[0];
    const float* Wq  = (const float*)d_in[1];
    const float* bq  = (const float*)d_in[2];
    const float* Wk  = (const float*)d_in[3];
    const float* bk  = (const float*)d_in[4];
    const float* Wv  = (const float*)d_in[5];
    const float* bv  = (const float*)d_in[6];
    const float* Wsq = (const float*)d_in[7];
    const float* bsq = (const float*)d_in[8];
    const float* Wsk = (const float*)d_in[9];
    const float* bsk = (const float*)d_in[10];
    const float* Wsv = (const float*)d_in[11];
    const float* bsv = (const float*)d_in[12];
    const float* lnw = (const float*)d_in[13];
    const float* lnb = (const float*)d_in[14];
    const float* Wp  = (const float*)d_in[15];
    const float* bp  = (const float*)d_in[16];
    float* out = (float*)d_out;

    // workspace layout (bytes):
    // Qpack 2MB | Kpack 2MB | VpackT 1MB | D 1MB | Pacc 4MB | Psum 0.5MB
    char* w = (char*)d_ws;
    uint*   Qpack  = (uint*)(w);
    uint*   Kpack  = (uint*)(w + (size_t)(2<<20));
    ushort* VpackT = (ushort*)(w + (size_t)(4<<20));
    float*  D      = (float*)(w + (size_t)(5<<20));
    float*  Pacc   = (float*)(w + (size_t)(6<<20));
    float*  Psum   = (float*)(w + (size_t)(10<<20));

    qkv_prepack_kernel<<<128, 256, 0, stream>>>(x, Wq, bq, Wk, bk, Wv, bv,
                                                Qpack, Kpack, VpackT);
    attn_mfma_kernel<<<2048, 256, 0, stream>>>(Qpack, Kpack, VpackT, Pacc, Psum);
    attn_reduce_kernel<4><<<128, 256, 0, stream>>>(Pacc, Psum, D);
    proj2_prepack_kernel<<<128, 256, 0, stream>>>(D, Wsq, bsq, Wsk, bsk, Wsv, bsv,
                                                  Qpack, Kpack, VpackT);
    attn_mfma_kernel<<<2048, 256, 0, stream>>>(Qpack, Kpack, VpackT, Pacc, Psum);
    attn_reduce_kernel<4><<<128, 256, 0, stream>>>(Pacc, Psum, D);
    head_kernel<<<512, 256, 0, stream>>>(D, lnw, lnb, Wp, bp, out);
}

// Round 14
// 234.920 us; speedup vs baseline: 1.3326x; 1.3326x over previous
//
#include <hip/hip_runtime.h>
#include <math.h>
#include <stdint.h>

// ---- problem constants ----
// x: [8,1,512,512] fp32; 8x8 patches -> 4096 patches/batch, pdim=64, HID=8.
// Output [8,512,512,3] fp32.
static constexpr float QSCALE = 0.35355339059327373f * 1.4426950408889634f; // SCALE*log2(e)

typedef _Float16 half8f __attribute__((ext_vector_type(8)));
typedef _Float16 half4f __attribute__((ext_vector_type(4)));
typedef float f32x4 __attribute__((ext_vector_type(4)));

__device__ __forceinline__ ushort f16_bits(float x) {
    return __builtin_bit_cast(ushort, (_Float16)x);
}
__device__ __forceinline__ float f16_back(ushort u) {
    return (float)__builtin_bit_cast(_Float16, u);
}
__device__ __forceinline__ uint pkrtz_bits(float a, float b) {
    auto v = __builtin_amdgcn_cvt_pkrtz(a, b);   // __fp16 ext_vector(2)
    return __builtin_bit_cast(uint, v);
}

// =====================================================================
// Packed-operand writer shared by both prepack kernels.
// Qpack[p]: 32 f16 slots = [q_hi(8), q_lo(8), q_hi(8), 0(8)]   (64 B)
// Kpack[p]: [k_hi(8), k_hi(8), k_lo(8), 0(8)]                  (64 B)
//   -> one 16x16x32 MFMA gives s = qh·kh + ql·kh + qh·kl  (fp32-class)
// VpackT[b][d][key] f16, d<8 = v_d, d=8 = 1.0 (rowsum column)
// =====================================================================
__device__ __forceinline__ void write_packed(
    int p, const float* qv, const float* kv, const float* vv,
    uint* __restrict__ Qpack, uint* __restrict__ Kpack, ushort* __restrict__ VpackT)
{
    uint qw[8], kw[8];
    #pragma unroll
    for (int i = 0; i < 4; ++i) {
        float q0 = qv[2*i], q1 = qv[2*i+1];
        ushort qh0 = f16_bits(q0), qh1 = f16_bits(q1);
        ushort ql0 = f16_bits(q0 - f16_back(qh0));
        ushort ql1 = f16_bits(q1 - f16_back(qh1));
        qw[i]   = (uint)qh0 | ((uint)qh1 << 16);
        qw[4+i] = (uint)ql0 | ((uint)ql1 << 16);
        float k0 = kv[2*i], k1 = kv[2*i+1];
        ushort kh0 = f16_bits(k0), kh1 = f16_bits(k1);
        ushort kl0 = f16_bits(k0 - f16_back(kh0));
        ushort kl1 = f16_bits(k1 - f16_back(kh1));
        kw[i]   = (uint)kh0 | ((uint)kh1 << 16);
        kw[4+i] = (uint)kl0 | ((uint)kl1 << 16);
    }
    uint4* Qp = (uint4*)(Qpack + (size_t)p*16);
    Qp[0] = make_uint4(qw[0],qw[1],qw[2],qw[3]);
    Qp[1] = make_uint4(qw[4],qw[5],qw[6],qw[7]);
    Qp[2] = make_uint4(qw[0],qw[1],qw[2],qw[3]);
    Qp[3] = make_uint4(0,0,0,0);
    uint4* Kp = (uint4*)(Kpack + (size_t)p*16);
    Kp[0] = make_uint4(kw[0],kw[1],kw[2],kw[3]);
    Kp[1] = make_uint4(kw[0],kw[1],kw[2],kw[3]);
    Kp[2] = make_uint4(kw[4],kw[5],kw[6],kw[7]);
    Kp[3] = make_uint4(0,0,0,0);
    int b = p >> 12, pidx = p & 4095;
    #pragma unroll
    for (int d = 0; d < 8; ++d)
        VpackT[((size_t)(b*16 + d))*4096 + pidx] = f16_bits(vv[d]);
    VpackT[((size_t)(b*16 + 8))*4096 + pidx] = 0x3C00; // 1.0
}

// =====================================================================
// Kernel 1: patchify + QKV projection (64 -> 8 x3) + f16 packing
// =====================================================================
__global__ __launch_bounds__(256) void qkv_prepack_kernel(
    const float* __restrict__ x,
    const float* __restrict__ Wq, const float* __restrict__ bq,
    const float* __restrict__ Wk, const float* __restrict__ bk,
    const float* __restrict__ Wv, const float* __restrict__ bv,
    uint* __restrict__ Qpack, uint* __restrict__ Kpack, ushort* __restrict__ VpackT)
{
    __shared__ float sW[64*24 + 24];
    for (int i = threadIdx.x; i < 64*24 + 24; i += 256) {
        float w;
        if (i < 1536) {
            int j = i / 24, c = i % 24;
            w = (c < 8) ? Wq[j*8 + c] : (c < 16) ? Wk[j*8 + (c-8)] : Wv[j*8 + (c-16)];
        } else {
            int c = i - 1536;
            w = (c < 8) ? bq[c] : (c < 16) ? bk[c-8] : bv[c-16];
        }
        sW[i] = w;
    }
    __syncthreads();

    int p = blockIdx.x * 256 + threadIdx.x;
    int b    = p >> 12;
    int pidx = p & 4095;
    int pr = pidx >> 6, pc = pidx & 63;
    const float* xb = x + ((size_t)(b*512 + pr*8)) * 512 + (size_t)pc*8;

    float acc[24];
    #pragma unroll
    for (int o = 0; o < 24; ++o) acc[o] = sW[1536 + o];
    #pragma unroll
    for (int i = 0; i < 8; ++i) {
        float4 a = *(const float4*)(xb + (size_t)i*512);
        float4 c = *(const float4*)(xb + (size_t)i*512 + 4);
        float px[8] = {a.x, a.y, a.z, a.w, c.x, c.y, c.z, c.w};
        #pragma unroll
        for (int jj = 0; jj < 8; ++jj) {
            float pj = px[jj];
            const float* w = &sW[(i*8 + jj)*24];
            #pragma unroll
            for (int o = 0; o < 24; ++o) acc[o] += pj * w[o];
        }
    }
    float qv[8], kv[8], vv[8];
    #pragma unroll
    for (int o = 0; o < 8; ++o) {
        qv[o] = acc[o] * QSCALE;
        kv[o] = acc[8+o];
        vv[o] = acc[16+o];
    }
    write_packed(p, qv, kv, vv, Qpack, Kpack, VpackT);
}

// =====================================================================
// MFMA flash-attention partial pass, v3.
// v2 post-mortem: serial load->use chain, VGPR=28 (no prefetch) ->
// latency-bound (MfmaUtil 7%, VALUBusy 15%). v3:
//  (a) 2 Q-tiles per wave (32 queries): same K/V loads feed 2x MFMA
//      pairs -> arithmetic intensity per load doubled.
//  (b) explicit 2-deep software prefetch with named rotating buffers
//      (kA/vA, kB/vB; manual t+=2 unroll) -> loads issue ~2 iters early.
// The 4 waves of a block share chunk c and read the same K/V stream
// (L1 reuse). Grid: 256 q-octos x 4 chunks = 1024 blocks x 256 thr.
// =====================================================================
__global__ __launch_bounds__(256) void attn_mfma_kernel(
    const uint* __restrict__ Qpack, const uint* __restrict__ Kpack,
    const ushort* __restrict__ VpackT,
    float* __restrict__ Pacc, float* __restrict__ Psum)
{
    int tid  = threadIdx.x;
    int lane = tid & 63, wid = tid >> 6;
    int blk  = blockIdx.x;
    int c     = blk & 3;
    int qocto = blk >> 2;             // 0..255
    int qduo  = qocto*4 + wid;        // 0..1023 (pair of q-tiles)
    int b   = qduo >> 7;              // batch (128 duos per batch)
    int qg0 = qduo * 32;              // global query base (32 queries)
    int kb  = b*4096 + c*1024;        // global key base
    int g = lane >> 4, cl = lane & 15;

    // Q B-fragments for the two 16-query tiles
    half8f qfrag0 = *(const half8f*)(Qpack + ((size_t)(qg0 + cl))*16 + g*4);
    half8f qfrag1 = *(const half8f*)(Qpack + ((size_t)(qg0 + 16 + cl))*16 + g*4);

    f32x4 acc0 = {0.f, 0.f, 0.f, 0.f};
    f32x4 acc1 = {0.f, 0.f, 0.f, 0.f};

    // per-lane streams: K row (key = kb + t*16 + cl, 16B at word g*4),
    // V row d=cl, 4 keys starting at kb + t*16 + g*4
    const uint*   kp = Kpack  + ((size_t)(kb + cl))*16 + g*4;
    const ushort* vp = VpackT + ((size_t)(b*16 + cl))*4096 + c*1024 + g*4;

    // 2-deep prefetch pipeline
    half8f kA = *(const half8f*)kp;
    uint2  vA = *(const uint2*)vp;
    half8f kB = *(const half8f*)(kp + 256);
    uint2  vB = *(const uint2*)(vp + 16);

    #define ATTN_COMPUTE(KF, VF)                                            \
    {                                                                       \
        f32x4 z = {0.f, 0.f, 0.f, 0.f};                                     \
        f32x4 s0 = __builtin_amdgcn_mfma_f32_16x16x32_f16(KF, qfrag0, z, 0, 0, 0); \
        f32x4 s1 = __builtin_amdgcn_mfma_f32_16x16x32_f16(KF, qfrag1, z, 0, 0, 0); \
        float e0 = __builtin_amdgcn_exp2f(s0[0]);                           \
        float e1 = __builtin_amdgcn_exp2f(s0[1]);                           \
        float e2 = __builtin_amdgcn_exp2f(s0[2]);                           \
        float e3 = __builtin_amdgcn_exp2f(s0[3]);                           \
        float e4 = __builtin_amdgcn_exp2f(s1[0]);                           \
        float e5 = __builtin_amdgcn_exp2f(s1[1]);                           \
        float e6 = __builtin_amdgcn_exp2f(s1[2]);                           \
        float e7 = __builtin_amdgcn_exp2f(s1[3]);                           \
        uint2 pu0 = make_uint2(pkrtz_bits(e0, e1), pkrtz_bits(e2, e3));     \
        uint2 pu1 = make_uint2(pkrtz_bits(e4, e5), pkrtz_bits(e6, e7));     \
        half4f pf0 = __builtin_bit_cast(half4f, pu0);                       \
        half4f pf1 = __builtin_bit_cast(half4f, pu1);                       \
        half4f vf = __builtin_bit_cast(half4f, VF);                         \
        acc0 = __builtin_amdgcn_mfma_f32_16x16x16f16(pf0, vf, acc0, 0, 0, 0); \
        acc1 = __builtin_amdgcn_mfma_f32_16x16x16f16(pf1, vf, acc1, 0, 0, 0); \
    }

    for (int t = 0; t < 64; t += 2) {
        if (t + 2 < 64) {
            half8f kN = *(const half8f*)(kp + 512);
            uint2  vN = *(const uint2*)(vp + 32);
            ATTN_COMPUTE(kA, vA);
            kA = kN; vA = vN;
        } else {
            ATTN_COMPUTE(kA, vA);
        }
        if (t + 3 < 64) {
            half8f kN = *(const half8f*)(kp + 768);
            uint2  vN = *(const uint2*)(vp + 48);
            ATTN_COMPUTE(kB, vB);
            kB = kN; vB = vN;
        } else {
            ATTN_COMPUTE(kB, vB);
        }
        kp += 512;   // 32 keys * 16 words
        vp += 32;    // 32 keys
    }
    #undef ATTN_COMPUTE

    // acc: lane -> O[q = base + g*4 + r][d = cl]; d=8 column = rowsum
    if (cl < 8) {
        #pragma unroll
        for (int r = 0; r < 4; ++r) {
            Pacc[((size_t)c*32768 + qg0 + g*4 + r)*8 + cl]      = acc0[r];
            Pacc[((size_t)c*32768 + qg0 + 16 + g*4 + r)*8 + cl] = acc1[r];
        }
    } else if (cl == 8) {
        #pragma unroll
        for (int r = 0; r < 4; ++r) {
            Psum[(size_t)c*32768 + qg0 + g*4 + r]      = acc0[r];
            Psum[(size_t)c*32768 + qg0 + 16 + g*4 + r] = acc1[r];
        }
    }
}

// Reduce NC partials per query -> normalized output [32768 x 8]
template<int NC>
__global__ __launch_bounds__(256) void attn_reduce_kernel(
    const float* __restrict__ Pacc, const float* __restrict__ Psum,
    float* __restrict__ O)
{
    int qg = blockIdx.x * 256 + threadIdx.x;
    float s = 0.f;
    float a[8] = {0,0,0,0,0,0,0,0};
    #pragma unroll
    for (int c = 0; c < NC; ++c) {
        s += Psum[(size_t)c*32768 + qg];
        const float4* pa = (const float4*)(Pacc + ((size_t)c*32768 + qg)*8);
        float4 x0 = pa[0], x1 = pa[1];
        a[0]+=x0.x; a[1]+=x0.y; a[2]+=x0.z; a[3]+=x0.w;
        a[4]+=x1.x; a[5]+=x1.y; a[6]+=x1.z; a[7]+=x1.w;
    }
    float inv = 1.0f / s;
    float4* o = (float4*)(O + (size_t)qg * 8);
    o[0] = make_float4(a[0]*inv, a[1]*inv, a[2]*inv, a[3]*inv);
    o[1] = make_float4(a[4]*inv, a[5]*inv, a[6]*inv, a[7]*inv);
}

// =====================================================================
// Kernel 4: second-stage projection (8 -> 8 x3) + f16 packing
// =====================================================================
__global__ __launch_bounds__(256) void proj2_prepack_kernel(
    const float* __restrict__ F,
    const float* __restrict__ Wsq, const float* __restrict__ bsq,
    const float* __restrict__ Wsk, const float* __restrict__ bsk,
    const float* __restrict__ Wsv, const float* __restrict__ bsv,
    uint* __restrict__ Qpack, uint* __restrict__ Kpack, ushort* __restrict__ VpackT)
{
    __shared__ float sW[8*24 + 24];
    for (int i = threadIdx.x; i < 8*24 + 24; i += 256) {
        float w;
        if (i < 192) {
            int j = i / 24, c = i % 24;
            w = (c < 8) ? Wsq[j*8 + c] : (c < 16) ? Wsk[j*8 + (c-8)] : Wsv[j*8 + (c-16)];
        } else {
            int c = i - 192;
            w = (c < 8) ? bsq[c] : (c < 16) ? bsk[c-8] : bsv[c-16];
        }
        sW[i] = w;
    }
    __syncthreads();

    int p = blockIdx.x * 256 + threadIdx.x;
    const float* f = F + (size_t)p * 8;
    float fv[8];
    {
        float4 a = ((const float4*)f)[0], c = ((const float4*)f)[1];
        fv[0]=a.x; fv[1]=a.y; fv[2]=a.z; fv[3]=a.w;
        fv[4]=c.x; fv[5]=c.y; fv[6]=c.z; fv[7]=c.w;
    }
    float acc[24];
    #pragma unroll
    for (int o = 0; o < 24; ++o) acc[o] = sW[192 + o];
    #pragma unroll
    for (int j = 0; j < 8; ++j) {
        float fj = fv[j];
        #pragma unroll
        for (int o = 0; o < 24; ++o) acc[o] += fj * sW[j*24 + o];
    }
    float qv[8], kv[8], vv[8];
    #pragma unroll
    for (int o = 0; o < 8; ++o) {
        qv[o] = acc[o] * QSCALE;
        kv[o] = acc[8+o];
        vv[o] = acc[16+o];
    }
    write_packed(p, qv, kv, vv, Qpack, Kpack, VpackT);
}

// =====================================================================
// Kernel 6: LayerNorm(8) + proj to 3 + clamped softplus + 8x upsample
// =====================================================================
__global__ __launch_bounds__(256) void head_kernel(
    const float* __restrict__ S,
    const float* __restrict__ ln_w, const float* __restrict__ ln_b,
    const float* __restrict__ Wp, const float* __restrict__ bp,
    float* __restrict__ out)
{
    int idx = blockIdx.x * 256 + threadIdx.x;   // 0..131071
    int p  = idx >> 2;
    int rq = idx & 3;
    int b    = p >> 12;
    int pidx = p & 4095;
    int pr = pidx >> 6, pc = pidx & 63;

    const float* s = S + (size_t)p * 8;
    float f[8];
    {
        float4 a = ((const float4*)s)[0], c = ((const float4*)s)[1];
        f[0]=a.x; f[1]=a.y; f[2]=a.z; f[3]=a.w;
        f[4]=c.x; f[5]=c.y; f[6]=c.z; f[7]=c.w;
    }
    float mu = 0.f;
    #pragma unroll
    for (int d = 0; d < 8; ++d) mu += f[d];
    mu *= 0.125f;
    float var = 0.f;
    #pragma unroll
    for (int d = 0; d < 8; ++d) { float t = f[d]-mu; var += t*t; }
    var *= 0.125f;
    float r = rsqrtf(var + 1e-5f);

    float o0 = bp[0], o1 = bp[1], o2 = bp[2];
    #pragma unroll
    for (int d = 0; d < 8; ++d) {
        float n = (f[d]-mu)*r*ln_w[d] + ln_b[d];
        o0 += n*Wp[d*3+0]; o1 += n*Wp[d*3+1]; o2 += n*Wp[d*3+2];
    }
    float o[3] = {o0, o1, o2};
    #pragma unroll
    for (int cix = 0; cix < 3; ++cix) {
        float xx = o[cix];
        float sp = fmaxf(xx, 0.f) + log1pf(expf(-fabsf(xx)));
        o[cix] = fminf(sp, 6.0f) + 1e-6f;
    }

    float4 f40 = make_float4(o[0], o[1], o[2], o[0]);
    float4 f41 = make_float4(o[1], o[2], o[0], o[1]);
    float4 f42 = make_float4(o[2], o[0], o[1], o[2]);
    float* ob = out + (((size_t)(b*512 + pr*8 + rq*2)) * 512 + (size_t)pc*8) * 3;
    #pragma unroll
    for (int i = 0; i < 2; ++i) {
        float4* row = (float4*)(ob + (size_t)i * 512 * 3);
        row[0]=f40; row[1]=f41; row[2]=f42; row[3]=f40; row[4]=f41; row[5]=f42;
    }
}

// =====================================================================
extern "C" void kernel_launch(void* const* d_in, const int* in_sizes, int n_in,
                              void* d_out, int out_size, void* d_ws, size_t ws_size,
                              hipStream_t stream)
{
    const float* x   = (const float*)d_in[0];
    const float* Wq  = (const float*)d_in[1];
    const float* bq  = (const float*)d_in[2];
    const float* Wk  = (const float*)d_in[3];
    const float* bk  = (const float*)d_in[4];
    const float* Wv  = (const float*)d_in[5];
    const float* bv  = (const float*)d_in[6];
    const float* Wsq = (const float*)d_in[7];
    const float* bsq = (const float*)d_in[8];
    const float* Wsk = (const float*)d_in[9];
    const float* bsk = (const float*)d_in[10];
    const float* Wsv = (const float*)d_in[11];
    const float* bsv = (const float*)d_in[12];
    const float* lnw = (const float*)d_in[13];
    const float* lnb = (const float*)d_in[14];
    const float* Wp  = (const float*)d_in[15];
    const float* bp  = (const float*)d_in[16];
    float* out = (float*)d_out;

    // workspace layout (bytes):
    // Qpack 2MB | Kpack 2MB | VpackT 1MB | D 1MB | Pacc 4MB | Psum 0.5MB
    char* w = (char*)d_ws;
    uint*   Qpack  = (uint*)(w);
    uint*   Kpack  = (uint*)(w + (size_t)(2<<20));
    ushort* VpackT = (ushort*)(w + (size_t)(4<<20));
    float*  D      = (float*)(w + (size_t)(5<<20));
    float*  Pacc   = (float*)(w + (size_t)(6<<20));
    float*  Psum   = (float*)(w + (size_t)(10<<20));

    qkv_prepack_kernel<<<128, 256, 0, stream>>>(x, Wq, bq, Wk, bk, Wv, bv,
                                                Qpack, Kpack, VpackT);
    attn_mfma_kernel<<<1024, 256, 0, stream>>>(Qpack, Kpack, VpackT, Pacc, Psum);
    attn_reduce_kernel<4><<<128, 256, 0, stream>>>(Pacc, Psum, D);
    proj2_prepack_kernel<<<128, 256, 0, stream>>>(D, Wsq, bsq, Wsk, bsk, Wsv, bsv,
                                                  Qpack, Kpack, VpackT);
    attn_mfma_kernel<<<1024, 256, 0, stream>>>(Qpack, Kpack, VpackT, Pacc, Psum);
    attn_reduce_kernel<4><<<128, 256, 0, stream>>>(Pacc, Psum, D);
    head_kernel<<<512, 256, 0, stream>>>(D, lnw, lnb, Wp, bp, out);
}

// Round 15
// 182.820 us; speedup vs baseline: 1.7124x; 1.2850x over previous
//
#include <hip/hip_runtime.h>
#include <math.h>
#include <stdint.h>

// ---- problem constants ----
// x: [8,1,512,512] fp32; 8x8 patches -> 4096 patches/batch, pdim=64, HID=8.
// Output [8,512,512,3] fp32.
static constexpr float QSCALE = 0.35355339059327373f * 1.4426950408889634f; // SCALE*log2(e)

typedef _Float16 half8f __attribute__((ext_vector_type(8)));
typedef _Float16 half4f __attribute__((ext_vector_type(4)));
typedef float f32x4 __attribute__((ext_vector_type(4)));

__device__ __forceinline__ ushort f16_bits(float x) {
    return __builtin_bit_cast(ushort, (_Float16)x);
}
__device__ __forceinline__ float f16_back(ushort u) {
    return (float)__builtin_bit_cast(_Float16, u);
}
__device__ __forceinline__ uint pkrtz_bits(float a, float b) {
    auto v = __builtin_amdgcn_cvt_pkrtz(a, b);   // __fp16 ext_vector(2)
    return __builtin_bit_cast(uint, v);
}

// =====================================================================
// Packed-operand writer shared by both prepack kernels.
// Qpack[p]: 32 f16 slots = [q_hi(8), q_lo(8), q_hi(8), 0(8)]   (64 B)
// Kpack[p]: [k_hi(8), k_hi(8), k_lo(8), 0(8)]                  (64 B)
//   -> one 16x16x32 MFMA gives s = qh·kh + ql·kh + qh·kl  (fp32-class)
// VpackT[b][d][key] f16, d<8 = v_d, d=8 = 1.0 (rowsum column)
// =====================================================================
__device__ __forceinline__ void write_packed(
    int p, const float* qv, const float* kv, const float* vv,
    uint* __restrict__ Qpack, uint* __restrict__ Kpack, ushort* __restrict__ VpackT)
{
    uint qw[8], kw[8];
    #pragma unroll
    for (int i = 0; i < 4; ++i) {
        float q0 = qv[2*i], q1 = qv[2*i+1];
        ushort qh0 = f16_bits(q0), qh1 = f16_bits(q1);
        ushort ql0 = f16_bits(q0 - f16_back(qh0));
        ushort ql1 = f16_bits(q1 - f16_back(qh1));
        qw[i]   = (uint)qh0 | ((uint)qh1 << 16);
        qw[4+i] = (uint)ql0 | ((uint)ql1 << 16);
        float k0 = kv[2*i], k1 = kv[2*i+1];
        ushort kh0 = f16_bits(k0), kh1 = f16_bits(k1);
        ushort kl0 = f16_bits(k0 - f16_back(kh0));
        ushort kl1 = f16_bits(k1 - f16_back(kh1));
        kw[i]   = (uint)kh0 | ((uint)kh1 << 16);
        kw[4+i] = (uint)kl0 | ((uint)kl1 << 16);
    }
    uint4* Qp = (uint4*)(Qpack + (size_t)p*16);
    Qp[0] = make_uint4(qw[0],qw[1],qw[2],qw[3]);
    Qp[1] = make_uint4(qw[4],qw[5],qw[6],qw[7]);
    Qp[2] = make_uint4(qw[0],qw[1],qw[2],qw[3]);
    Qp[3] = make_uint4(0,0,0,0);
    uint4* Kp = (uint4*)(Kpack + (size_t)p*16);
    Kp[0] = make_uint4(kw[0],kw[1],kw[2],kw[3]);
    Kp[1] = make_uint4(kw[0],kw[1],kw[2],kw[3]);
    Kp[2] = make_uint4(kw[4],kw[5],kw[6],kw[7]);
    Kp[3] = make_uint4(0,0,0,0);
    int b = p >> 12, pidx = p & 4095;
    #pragma unroll
    for (int d = 0; d < 8; ++d)
        VpackT[((size_t)(b*16 + d))*4096 + pidx] = f16_bits(vv[d]);
    VpackT[((size_t)(b*16 + 8))*4096 + pidx] = 0x3C00; // 1.0
}

// =====================================================================
// Kernel 1: patchify + QKV projection (64 -> 8 x3) + f16 packing
// =====================================================================
__global__ __launch_bounds__(256) void qkv_prepack_kernel(
    const float* __restrict__ x,
    const float* __restrict__ Wq, const float* __restrict__ bq,
    const float* __restrict__ Wk, const float* __restrict__ bk,
    const float* __restrict__ Wv, const float* __restrict__ bv,
    uint* __restrict__ Qpack, uint* __restrict__ Kpack, ushort* __restrict__ VpackT)
{
    __shared__ float sW[64*24 + 24];
    for (int i = threadIdx.x; i < 64*24 + 24; i += 256) {
        float w;
        if (i < 1536) {
            int j = i / 24, c = i % 24;
            w = (c < 8) ? Wq[j*8 + c] : (c < 16) ? Wk[j*8 + (c-8)] : Wv[j*8 + (c-16)];
        } else {
            int c = i - 1536;
            w = (c < 8) ? bq[c] : (c < 16) ? bk[c-8] : bv[c-16];
        }
        sW[i] = w;
    }
    __syncthreads();

    int p = blockIdx.x * 256 + threadIdx.x;
    int b    = p >> 12;
    int pidx = p & 4095;
    int pr = pidx >> 6, pc = pidx & 63;
    const float* xb = x + ((size_t)(b*512 + pr*8)) * 512 + (size_t)pc*8;

    float acc[24];
    #pragma unroll
    for (int o = 0; o < 24; ++o) acc[o] = sW[1536 + o];
    #pragma unroll
    for (int i = 0; i < 8; ++i) {
        float4 a = *(const float4*)(xb + (size_t)i*512);
        float4 c = *(const float4*)(xb + (size_t)i*512 + 4);
        float px[8] = {a.x, a.y, a.z, a.w, c.x, c.y, c.z, c.w};
        #pragma unroll
        for (int jj = 0; jj < 8; ++jj) {
            float pj = px[jj];
            const float* w = &sW[(i*8 + jj)*24];
            #pragma unroll
            for (int o = 0; o < 24; ++o) acc[o] += pj * w[o];
        }
    }
    float qv[8], kv[8], vv[8];
    #pragma unroll
    for (int o = 0; o < 8; ++o) {
        qv[o] = acc[o] * QSCALE;
        kv[o] = acc[8+o];
        vv[o] = acc[16+o];
    }
    write_packed(p, qv, kv, vv, Qpack, Kpack, VpackT);
}

// =====================================================================
// MFMA flash-attention partial pass, v4: LDS double-buffer + T14 split.
// v3 post-mortem: compiler re-serialized the register prefetch (VGPR=28,
// ~470cyc/iter = 1 load latency). v4 decouples structurally:
// per 64-key tile: {issue next tile's global loads (16B/thread) ->
// compute current tile from LDS -> ds_write staged regs -> barrier}.
// Load->ds_write gap = full compute phase (~400cyc) hides L2 latency.
// Block: 4 waves x 2 q-tiles = 128 queries, share K/V chunk (NC=8).
// LDS: K rows padded KW=20 words, V rows VW=36 (16B-aligned, low bank
// aliasing). Grid: 256 q-groups x 8 chunks = 2048 blocks -> 8 waves/SIMD.
// =====================================================================
template<int NC>
__global__ __launch_bounds__(256) void attn_mfma_kernel(
    const uint* __restrict__ Qpack, const uint* __restrict__ Kpack,
    const ushort* __restrict__ VpackT,
    float* __restrict__ Pacc, float* __restrict__ Psum)
{
    constexpr int CH = 4096 / NC;     // keys per chunk (512)
    constexpr int NT = CH / 64;       // 64-key tiles per chunk (8)
    constexpr int KW = 20;            // LDS words per K row (16 data + 4 pad)
    constexpr int VW = 36;            // LDS words per V d-row (32 data + 4 pad)
    __shared__ uint Kl[2][64*KW];     // 5 KB x2
    __shared__ uint Vl[2][16*VW];     // 2.25 KB x2

    int tid  = threadIdx.x;
    int lane = tid & 63, wid = tid >> 6;
    int blk  = blockIdx.x;
    int c     = blk & (NC-1);
    int qgrp  = blk >> 3;             // 0..255 (NC=8)
    int qg0   = qgrp*128 + wid*32;    // first of this wave's 32 queries
    int b     = qg0 >> 12;            // batch
    int kb    = b*4096 + c*CH;        // global key base
    int g = lane >> 4, cl = lane & 15;

    // Q B-fragments for the wave's two 16-query tiles
    half8f qfrag0 = *(const half8f*)(Qpack + ((size_t)(qg0 + cl))*16 + g*4);
    half8f qfrag1 = *(const half8f*)(Qpack + ((size_t)(qg0 + 16 + cl))*16 + g*4);

    f32x4 acc0 = {0.f, 0.f, 0.f, 0.f};
    f32x4 acc1 = {0.f, 0.f, 0.f, 0.f};

    // staging helpers: 16B/thread K (all 256 thr), 16B/thread V (thr<128)
    auto ldK = [&](int st) {
        return *(const uint4*)(Kpack + ((size_t)(kb + st*64 + (tid>>2)))*16 + (tid&3)*4);
    };
    auto ldV = [&](int st) {
        return *(const uint4*)(VpackT + ((size_t)(b*16 + (tid>>3)))*4096 + c*CH + st*64 + (tid&7)*8);
    };
    auto dsw = [&](int buf, uint4 kr, uint4 vr) {
        *(uint4*)&Kl[buf][(tid>>2)*KW + (tid&3)*4] = kr;
        if (tid < 128)
            *(uint4*)&Vl[buf][(tid>>3)*VW + (tid&7)*4] = vr;
    };

    auto compute = [&](const uint* Kb, const uint* Vb) {
        #pragma unroll
        for (int tt = 0; tt < 4; ++tt) {
            half8f kf = *(const half8f*)&Kb[(tt*16 + cl)*KW + g*4];
            f32x4 z = {0.f, 0.f, 0.f, 0.f};
            f32x4 s0 = __builtin_amdgcn_mfma_f32_16x16x32_f16(kf, qfrag0, z, 0, 0, 0);
            f32x4 s1 = __builtin_amdgcn_mfma_f32_16x16x32_f16(kf, qfrag1, z, 0, 0, 0);
            float e0 = __builtin_amdgcn_exp2f(s0[0]);
            float e1 = __builtin_amdgcn_exp2f(s0[1]);
            float e2 = __builtin_amdgcn_exp2f(s0[2]);
            float e3 = __builtin_amdgcn_exp2f(s0[3]);
            float e4 = __builtin_amdgcn_exp2f(s1[0]);
            float e5 = __builtin_amdgcn_exp2f(s1[1]);
            float e6 = __builtin_amdgcn_exp2f(s1[2]);
            float e7 = __builtin_amdgcn_exp2f(s1[3]);
            uint2 pu0 = make_uint2(pkrtz_bits(e0, e1), pkrtz_bits(e2, e3));
            uint2 pu1 = make_uint2(pkrtz_bits(e4, e5), pkrtz_bits(e6, e7));
            half4f pf0 = __builtin_bit_cast(half4f, pu0);
            half4f pf1 = __builtin_bit_cast(half4f, pu1);
            uint2 vu = *(const uint2*)&Vb[cl*VW + tt*8 + g*2];
            half4f vf = __builtin_bit_cast(half4f, vu);
            acc0 = __builtin_amdgcn_mfma_f32_16x16x16f16(pf0, vf, acc0, 0, 0, 0);
            acc1 = __builtin_amdgcn_mfma_f32_16x16x16f16(pf1, vf, acc1, 0, 0, 0);
        }
    };

    // prologue: stage tile 0 into buffer A
    {
        uint4 k0 = ldK(0);
        uint4 v0 = (tid < 128) ? ldV(0) : make_uint4(0,0,0,0);
        dsw(0, k0, v0);
    }
    __syncthreads();

    for (int st = 0; st < NT; st += 2) {
        // buffer A active
        uint4 k1, v1;
        if (st + 1 < NT) {                       // issue-early
            k1 = ldK(st+1);
            v1 = (tid < 128) ? ldV(st+1) : make_uint4(0,0,0,0);
        }
        compute(Kl[0], Vl[0]);
        if (st + 1 < NT) dsw(1, k1, v1);         // write-late
        __syncthreads();
        if (st + 1 < NT) {
            uint4 k2, v2;
            if (st + 2 < NT) {
                k2 = ldK(st+2);
                v2 = (tid < 128) ? ldV(st+2) : make_uint4(0,0,0,0);
            }
            compute(Kl[1], Vl[1]);
            if (st + 2 < NT) dsw(0, k2, v2);
            __syncthreads();
        }
    }

    // acc: lane -> O[q = base + g*4 + r][d = cl]; d=8 column = rowsum
    if (cl < 8) {
        #pragma unroll
        for (int r = 0; r < 4; ++r) {
            Pacc[((size_t)c*32768 + qg0 + g*4 + r)*8 + cl]      = acc0[r];
            Pacc[((size_t)c*32768 + qg0 + 16 + g*4 + r)*8 + cl] = acc1[r];
        }
    } else if (cl == 8) {
        #pragma unroll
        for (int r = 0; r < 4; ++r) {
            Psum[(size_t)c*32768 + qg0 + g*4 + r]      = acc0[r];
            Psum[(size_t)c*32768 + qg0 + 16 + g*4 + r] = acc1[r];
        }
    }
}

// =====================================================================
// Kernel 3: fused reduce(NC partials) + second-stage proj + f16 packing
// =====================================================================
template<int NC>
__global__ __launch_bounds__(256) void proj2_fused_kernel(
    const float* __restrict__ Pacc, const float* __restrict__ Psum,
    const float* __restrict__ Wsq, const float* __restrict__ bsq,
    const float* __restrict__ Wsk, const float* __restrict__ bsk,
    const float* __restrict__ Wsv, const float* __restrict__ bsv,
    uint* __restrict__ Qpack, uint* __restrict__ Kpack, ushort* __restrict__ VpackT)
{
    __shared__ float sW[8*24 + 24];
    for (int i = threadIdx.x; i < 8*24 + 24; i += 256) {
        float w;
        if (i < 192) {
            int j = i / 24, c = i % 24;
            w = (c < 8) ? Wsq[j*8 + c] : (c < 16) ? Wsk[j*8 + (c-8)] : Wsv[j*8 + (c-16)];
        } else {
            int c = i - 192;
            w = (c < 8) ? bsq[c] : (c < 16) ? bsk[c-8] : bsv[c-16];
        }
        sW[i] = w;
    }
    __syncthreads();

    int p = blockIdx.x * 256 + threadIdx.x;

    // reduce NC chunk partials
    float s = 0.f;
    float a[8] = {0,0,0,0,0,0,0,0};
    #pragma unroll
    for (int c = 0; c < NC; ++c) {
        s += Psum[(size_t)c*32768 + p];
        const float4* pa = (const float4*)(Pacc + ((size_t)c*32768 + p)*8);
        float4 x0 = pa[0], x1 = pa[1];
        a[0]+=x0.x; a[1]+=x0.y; a[2]+=x0.z; a[3]+=x0.w;
        a[4]+=x1.x; a[5]+=x1.y; a[6]+=x1.z; a[7]+=x1.w;
    }
    float inv = 1.0f / s;
    float fv[8];
    #pragma unroll
    for (int d = 0; d < 8; ++d) fv[d] = a[d] * inv;

    float acc[24];
    #pragma unroll
    for (int o = 0; o < 24; ++o) acc[o] = sW[192 + o];
    #pragma unroll
    for (int j = 0; j < 8; ++j) {
        float fj = fv[j];
        #pragma unroll
        for (int o = 0; o < 24; ++o) acc[o] += fj * sW[j*24 + o];
    }
    float qv[8], kv[8], vv[8];
    #pragma unroll
    for (int o = 0; o < 8; ++o) {
        qv[o] = acc[o] * QSCALE;
        kv[o] = acc[8+o];
        vv[o] = acc[16+o];
    }
    write_packed(p, qv, kv, vv, Qpack, Kpack, VpackT);
}

// =====================================================================
// Kernel 5: fused reduce + LayerNorm(8) + proj(3) + softplus + upsample
// one thread per patch; writes 8 rows x 24 floats
// =====================================================================
template<int NC>
__global__ __launch_bounds__(256) void head_fused_kernel(
    const float* __restrict__ Pacc, const float* __restrict__ Psum,
    const float* __restrict__ ln_w, const float* __restrict__ ln_b,
    const float* __restrict__ Wp, const float* __restrict__ bp,
    float* __restrict__ out)
{
    int p = blockIdx.x * 256 + threadIdx.x;   // 0..32767
    int b    = p >> 12;
    int pidx = p & 4095;
    int pr = pidx >> 6, pc = pidx & 63;

    float s = 0.f;
    float f[8] = {0,0,0,0,0,0,0,0};
    #pragma unroll
    for (int c = 0; c < NC; ++c) {
        s += Psum[(size_t)c*32768 + p];
        const float4* pa = (const float4*)(Pacc + ((size_t)c*32768 + p)*8);
        float4 x0 = pa[0], x1 = pa[1];
        f[0]+=x0.x; f[1]+=x0.y; f[2]+=x0.z; f[3]+=x0.w;
        f[4]+=x1.x; f[5]+=x1.y; f[6]+=x1.z; f[7]+=x1.w;
    }
    float inv = 1.0f / s;
    #pragma unroll
    for (int d = 0; d < 8; ++d) f[d] *= inv;

    float mu = 0.f;
    #pragma unroll
    for (int d = 0; d < 8; ++d) mu += f[d];
    mu *= 0.125f;
    float var = 0.f;
    #pragma unroll
    for (int d = 0; d < 8; ++d) { float t = f[d]-mu; var += t*t; }
    var *= 0.125f;
    float r = rsqrtf(var + 1e-5f);

    float o0 = bp[0], o1 = bp[1], o2 = bp[2];
    #pragma unroll
    for (int d = 0; d < 8; ++d) {
        float n = (f[d]-mu)*r*ln_w[d] + ln_b[d];
        o0 += n*Wp[d*3+0]; o1 += n*Wp[d*3+1]; o2 += n*Wp[d*3+2];
    }
    float o[3] = {o0, o1, o2};
    #pragma unroll
    for (int cix = 0; cix < 3; ++cix) {
        float xx = o[cix];
        float sp = fmaxf(xx, 0.f) + log1pf(expf(-fabsf(xx)));
        o[cix] = fminf(sp, 6.0f) + 1e-6f;
    }

    float4 f40 = make_float4(o[0], o[1], o[2], o[0]);
    float4 f41 = make_float4(o[1], o[2], o[0], o[1]);
    float4 f42 = make_float4(o[2], o[0], o[1], o[2]);
    float* ob = out + (((size_t)(b*512 + pr*8)) * 512 + (size_t)pc*8) * 3;
    #pragma unroll
    for (int i = 0; i < 8; ++i) {
        float4* row = (float4*)(ob + (size_t)i * 512 * 3);
        row[0]=f40; row[1]=f41; row[2]=f42; row[3]=f40; row[4]=f41; row[5]=f42;
    }
}

// =====================================================================
extern "C" void kernel_launch(void* const* d_in, const int* in_sizes, int n_in,
                              void* d_out, int out_size, void* d_ws, size_t ws_size,
                              hipStream_t stream)
{
    const float* x   = (const float*)d_in[0];
    const float* Wq  = (const float*)d_in[1];
    const float* bq  = (const float*)d_in[2];
    const float* Wk  = (const float*)d_in[3];
    const float* bk  = (const float*)d_in[4];
    const float* Wv  = (const float*)d_in[5];
    const float* bv  = (const float*)d_in[6];
    const float* Wsq = (const float*)d_in[7];
    const float* bsq = (const float*)d_in[8];
    const float* Wsk = (const float*)d_in[9];
    const float* bsk = (const float*)d_in[10];
    const float* Wsv = (const float*)d_in[11];
    const float* bsv = (const float*)d_in[12];
    const float* lnw = (const float*)d_in[13];
    const float* lnb = (const float*)d_in[14];
    const float* Wp  = (const float*)d_in[15];
    const float* bp  = (const float*)d_in[16];
    float* out = (float*)d_out;

    // workspace layout (bytes):
    // Qpack 2MB | Kpack 2MB | VpackT 1MB | Pacc 8MB | Psum 1MB  = 14MB
    char* w = (char*)d_ws;
    uint*   Qpack  = (uint*)(w);
    uint*   Kpack  = (uint*)(w + (size_t)(2<<20));
    ushort* VpackT = (ushort*)(w + (size_t)(4<<20));
    float*  Pacc   = (float*)(w + (size_t)(5<<20));
    float*  Psum   = (float*)(w + (size_t)(13<<20));

    constexpr int NC = 8;

    qkv_prepack_kernel<<<128, 256, 0, stream>>>(x, Wq, bq, Wk, bk, Wv, bv,
                                                Qpack, Kpack, VpackT);
    attn_mfma_kernel<NC><<<256*NC, 256, 0, stream>>>(Qpack, Kpack, VpackT, Pacc, Psum);
    proj2_fused_kernel<NC><<<128, 256, 0, stream>>>(Pacc, Psum,
                                                    Wsq, bsq, Wsk, bsk, Wsv, bsv,
                                                    Qpack, Kpack, VpackT);
    attn_mfma_kernel<NC><<<256*NC, 256, 0, stream>>>(Qpack, Kpack, VpackT, Pacc, Psum);
    head_fused_kernel<NC><<<128, 256, 0, stream>>>(Pacc, Psum, lnw, lnb, Wp, bp, out);
}